// Round 13
// baseline (94.520 us; speedup 1.0000x reference)
//
#include <hip/hip_runtime.h>

#define RNK 32
#define VOC 32000
#define BSZ 512
#define SEQ 24

#define DEPTH 4                   // tokens in flight per chain wave
#define NSLOT 5                   // DEPTH+1 -> rotation never aliases (absmax-proven)

#define TP_BLOCKS 500
#define TILES_PER_BLOCK 8         // 8 v per tile; 500*8*8 = 32000 exactly

// ws layout: gm[1024]f32 | bitmap[1024]u32 | staged[VOC][32][32] bf16 (65.5 MB)
#define WS_NEEDED ((size_t)8192 + (size_t)VOC * RNK * RNK * 2)

typedef const __attribute__((address_space(1))) void* as1_cvp;
typedef __attribute__((address_space(3))) void* as3_vp;

// ===========================================================================
// STAGED PATH
// ===========================================================================

// Token-usage bitmap: 12288 tokens -> 1024 words.
__global__ __launch_bounds__(256) void bitmap_kernel(const int* __restrict__ y,
                                                     unsigned* __restrict__ bitmap) {
    const int tok = y[blockIdx.x * 256 + threadIdx.x];
    atomicOr(&bitmap[tok >> 5], 1u << (tok & 31));
}

// Tiled transpose + reduce. Per (tile of 8 v, r): ONE 1-KB-contiguous wave
// load (16 lines/request). LDS transpose (quad-XOR baked in); marked tokens
// written as one 2-KB contiguous bf16 burst; gm accumulated in registers,
// atomics once at kernel end. No sub-line scatter anywhere.
__global__ __launch_bounds__(256) void transpose_reduce_kernel(
        const float* __restrict__ core, float* __restrict__ gm,
        const unsigned* __restrict__ bitmap, unsigned short* __restrict__ staged) {
    __shared__ float ldsT[8][32][32];         // 32 KB: [v_loc][r][swizzled quads]
    const int tid  = threadIdx.x;
    const int lane = tid & 63;
    const int w    = tid >> 6;                // wave 0..3 owns r = w*8 .. w*8+7
    const int vloc = lane >> 3;               // 0..7: v within tile
    const int q    = lane & 7;                // source col quad (4 floats)

    float acc[8][4];                          // gm partials for this wave's 8 r's
    #pragma unroll
    for (int i = 0; i < 8; ++i) {
        acc[i][0] = 0.f; acc[i][1] = 0.f; acc[i][2] = 0.f; acc[i][3] = 0.f;
    }

    for (int j = 0; j < TILES_PER_BLOCK; ++j) {
        const int v0 = (blockIdx.x * TILES_PER_BLOCK + j) * 8;

        // 8 x 1KB contiguous wave-loads (r = w*8+i), all in flight together
        float4 m[8];
        #pragma unroll
        for (int i = 0; i < 8; ++i) {
            const int r = w * 8 + i;
            m[i] = *(const float4*)(core + (size_t)r * VOC * RNK
                                         + (size_t)(v0 + vloc) * RNK + q * 4);
        }

        __syncthreads();                      // prev tile's writeout done

        #pragma unroll
        for (int i = 0; i < 8; ++i) {
            const int r = w * 8 + i;
            // swizzled store: ldsT[vloc][r][(q^(r&7))*4+k] = M[r][q*4+k]
            *(float4*)&ldsT[vloc][r][(q ^ (r & 7)) * 4] = m[i];
            // gm partial: butterfly over the v_loc bits (xor 8/16/32)
            float a0 = m[i].x, a1 = m[i].y, a2 = m[i].z, a3 = m[i].w;
            #pragma unroll
            for (int mask = 8; mask <= 32; mask <<= 1) {
                a0 += __shfl_xor(a0, mask, 64);
                a1 += __shfl_xor(a1, mask, 64);
                a2 += __shfl_xor(a2, mask, 64);
                a3 += __shfl_xor(a3, mask, 64);
            }
            if (lane < 8) {                   // lane q holds sum over 8 v for quad q
                acc[i][0] += a0; acc[i][1] += a1; acc[i][2] += a2; acc[i][3] += a3;
            }
        }
        __syncthreads();                      // all r rows staged in LDS

        // write out marked tokens: 2 KB contiguous bf16 each (full lines)
        #pragma unroll
        for (int vl = 0; vl < 8; ++vl) {
            const int v = v0 + vl;
            if (bitmap[v >> 5] & (1u << (v & 31))) {
                const int rr = tid >> 3, qq = tid & 7;
                const float* src = &ldsT[vl][rr][qq * 4];
                ushort4 h;
                h.x = (unsigned short)(__float_as_uint(src[0]) >> 16);
                h.y = (unsigned short)(__float_as_uint(src[1]) >> 16);
                h.z = (unsigned short)(__float_as_uint(src[2]) >> 16);
                h.w = (unsigned short)(__float_as_uint(src[3]) >> 16);
                *(ushort4*)(staged + (size_t)v * 1024 + rr * 32 + qq * 4) = h;
            }
        }
    }

    if (lane < 8) {                           // 1024 atomics/block, 500/address total
        #pragma unroll
        for (int i = 0; i < 8; ++i) {
            const int r = w * 8 + i;
            #pragma unroll
            for (int k = 0; k < 4; ++k)
                atomicAdd(&gm[r * RNK + lane * 4 + k], acc[i][k]);
        }
    }
}

// Chain from staged: each token = ONE contiguous 2 KB read (2 x gl_lds).
// DEPTH-4 / NSLOT-5 alias-free schedule; swizzled la[] (R9-proven formula).
// Block BSZ computes z from gm (kernel-boundary ordered).
__global__ __launch_bounds__(64) void chainz_staged_kernel(
        const unsigned short* __restrict__ staged, const int* __restrict__ y,
        const float* __restrict__ alpha, const float* __restrict__ beta,
        const float* __restrict__ gm, float* __restrict__ out) {
    __shared__ unsigned short mbufh[NSLOT * 1024];       // 10 KB
    const int tid = threadIdx.x;                          // == lane

    if (blockIdx.x < BSZ) {
        const int lane = tid;
        const int s    = lane & 31;
        const int half = lane >> 5;
        const int row  = blockIdx.x;

        int ytok = (lane < SEQ) ? y[row * SEQ + lane] : 0;
        float state = alpha[s];
        const float betav = beta[s];

        // swizzled LDS offsets (ushort units): M[r=16h+i][s]
        int la[16];
        #pragma unroll
        for (int i = 0; i < 16; ++i) {
            const int r = half * 16 + i;
            la[i] = r * 32 + (((s >> 2) ^ (r & 7)) << 2) + (s & 3);
        }

        asm volatile("s_waitcnt vmcnt(0)" ::: "memory");  // vmcnt counts gl_lds only

        #pragma unroll
        for (int pt = 0; pt < DEPTH; ++pt) {              // tokens 0..3 -> slots 0..3
            const int tok = __shfl(ytok, pt, 64);
            const unsigned short* src = staged + (size_t)tok * 1024;
            #pragma unroll
            for (int j = 0; j < 2; ++j)
                __builtin_amdgcn_global_load_lds((as1_cvp)(src + j * 512 + lane * 8),
                                                 (as3_vp)(mbufh + pt * 1024 + j * 512), 16, 0, 0);
        }

        #pragma unroll
        for (int t = 0; t < SEQ; ++t) {                   // literal waits (2 ops/token)
            if      (t <= SEQ - 4) asm volatile("s_waitcnt vmcnt(6)" ::: "memory");
            else if (t == SEQ - 3) asm volatile("s_waitcnt vmcnt(4)" ::: "memory");
            else if (t == SEQ - 2) asm volatile("s_waitcnt vmcnt(2)" ::: "memory");
            else                   asm volatile("s_waitcnt vmcnt(0)" ::: "memory");
            __builtin_amdgcn_sched_barrier(0);

            const unsigned short* M = mbufh + (t % NSLOT) * 1024;
            float a0 = 0.f, a1 = 0.f, a2 = 0.f, a3 = 0.f;
            #pragma unroll
            for (int i = 0; i < 16; i += 4) {
                a0 = fmaf(__shfl(state, half*16+i+0, 64), __uint_as_float((unsigned)M[la[i+0]] << 16), a0);
                a1 = fmaf(__shfl(state, half*16+i+1, 64), __uint_as_float((unsigned)M[la[i+1]] << 16), a1);
                a2 = fmaf(__shfl(state, half*16+i+2, 64), __uint_as_float((unsigned)M[la[i+2]] << 16), a2);
                a3 = fmaf(__shfl(state, half*16+i+3, 64), __uint_as_float((unsigned)M[la[i+3]] << 16), a3);
            }
            const float acc = (a0 + a1) + (a2 + a3);
            state = acc + __shfl_xor(acc, 32, 64);

            if (t + DEPTH < SEQ) {
                const int tok = __shfl(ytok, t + DEPTH, 64);
                const unsigned short* src = staged + (size_t)tok * 1024;
                unsigned short* dst = mbufh + ((t + DEPTH) % NSLOT) * 1024;
                #pragma unroll
                for (int j = 0; j < 2; ++j)
                    __builtin_amdgcn_global_load_lds((as1_cvp)(src + j * 512 + lane * 8),
                                                     (as3_vp)(dst + j * 512), 16, 0, 0);
            }
        }

        float p = state * betav;
        #pragma unroll
        for (int m = 16; m >= 1; m >>= 1) p += __shfl_xor(p, m, 64);
        if (lane == 0) out[row] = p;
    } else {
        const int s    = tid & 31;
        const int half = tid >> 5;
        float col[16];
        #pragma unroll
        for (int i = 0; i < 16; ++i) col[i] = gm[(half * 16 + i) * RNK + s];
        float v = alpha[s];
        #pragma unroll
        for (int t = 0; t < SEQ; ++t) {
            float a0 = 0.f, a1 = 0.f, a2 = 0.f, a3 = 0.f;
            #pragma unroll
            for (int i = 0; i < 16; i += 4) {
                a0 = fmaf(__shfl(v, half * 16 + i + 0, 64), col[i + 0], a0);
                a1 = fmaf(__shfl(v, half * 16 + i + 1, 64), col[i + 1], a1);
                a2 = fmaf(__shfl(v, half * 16 + i + 2, 64), col[i + 2], a2);
                a3 = fmaf(__shfl(v, half * 16 + i + 3, 64), col[i + 3], a3);
            }
            const float acc = (a0 + a1) + (a2 + a3);
            v = acc + __shfl_xor(acc, 32, 64);
        }
        float z = v * beta[s];
        #pragma unroll
        for (int m = 16; m >= 1; m >>= 1) z += __shfl_xor(z, m, 64);
        if (tid == 0) out[BSZ] = z * (float)BSZ;
    }
}

// ===========================================================================
// FALLBACK PATH: R5 fused kernel verbatim (42.3 us proven) if ws is too small
// ===========================================================================
#define FB_BLOCK 128
#define FB_CHAIN_BLOCKS 256
#define FB_REDUCE_BLOCKS 4000
#define FB_DEPTH 6

__device__ __forceinline__ void fb_issue_load(const float* src_tok, float* lds_base, int lane) {
    const int r  = lane >> 3;
    const int c0 = (lane & 7) * 4;
    #pragma unroll
    for (int j = 0; j < 4; ++j) {
        const float* src = src_tok + (size_t)(j * 8 + r) * ((size_t)VOC * RNK) + c0;
        __builtin_amdgcn_global_load_lds((as1_cvp)src, (as3_vp)(lds_base + j * 256), 16, 0, 0);
    }
}

__global__ __launch_bounds__(FB_BLOCK) void fb_fused_kernel(const float* __restrict__ core,
                                                            const int* __restrict__ y,
                                                            const float* __restrict__ alpha,
                                                            const float* __restrict__ beta,
                                                            float* __restrict__ out,
                                                            float* __restrict__ gm) {
    __shared__ float shmem[2 * FB_DEPTH * 1024 + RNK];
    if (blockIdx.x < FB_CHAIN_BLOCKS) {
        const int tid  = threadIdx.x;
        const int lane = tid & 63;
        const int w    = tid >> 6;
        const int s    = lane & 31;
        const int half = lane >> 5;
        const int row  = blockIdx.x * 2 + w;
        float* mybuf = shmem + w * (FB_DEPTH * 1024);

        int   ytok  = (lane < SEQ) ? y[row * SEQ + lane] : 0;
        float state = alpha[s];
        float betav = beta[s];
        asm volatile("s_waitcnt vmcnt(0)" ::: "memory");

        #pragma unroll
        for (int pt = 0; pt < FB_DEPTH; ++pt) {
            const int tok = __shfl(ytok, pt, 64);
            fb_issue_load(core + (size_t)tok * RNK, mybuf + pt * 1024, lane);
        }
        #pragma unroll
        for (int t = 0; t < SEQ; ++t) {
            if      (t <= SEQ - 6) asm volatile("s_waitcnt vmcnt(20)" ::: "memory");
            else if (t == SEQ - 5) asm volatile("s_waitcnt vmcnt(16)" ::: "memory");
            else if (t == SEQ - 4) asm volatile("s_waitcnt vmcnt(12)" ::: "memory");
            else if (t == SEQ - 3) asm volatile("s_waitcnt vmcnt(8)"  ::: "memory");
            else if (t == SEQ - 2) asm volatile("s_waitcnt vmcnt(4)"  ::: "memory");
            else                   asm volatile("s_waitcnt vmcnt(0)"  ::: "memory");
            __builtin_amdgcn_sched_barrier(0);

            if (t + FB_DEPTH < SEQ) {
                const int tok = __shfl(ytok, t + FB_DEPTH, 64);
                fb_issue_load(core + (size_t)tok * RNK,
                              mybuf + ((t + FB_DEPTH) % FB_DEPTH) * 1024, lane);
            }
            const float* M = mybuf + (t % FB_DEPTH) * 1024;
            float a0 = 0.f, a1 = 0.f, a2 = 0.f, a3 = 0.f;
            #pragma unroll
            for (int i = 0; i < 16; i += 4) {
                a0 = fmaf(__shfl(state, half * 16 + i + 0, 64), M[(half * 16 + i + 0) * 32 + s], a0);
                a1 = fmaf(__shfl(state, half * 16 + i + 1, 64), M[(half * 16 + i + 1) * 32 + s], a1);
                a2 = fmaf(__shfl(state, half * 16 + i + 2, 64), M[(half * 16 + i + 2) * 32 + s], a2);
                a3 = fmaf(__shfl(state, half * 16 + i + 3, 64), M[(half * 16 + i + 3) * 32 + s], a3);
            }
            const float acc = (a0 + a1) + (a2 + a3);
            state = acc + __shfl_xor(acc, 32, 64);
        }
        float p = state * betav;
        #pragma unroll
        for (int m = 16; m >= 1; m >>= 1) p += __shfl_xor(p, m, 64);
        if (lane == 0) out[row] = p;
    } else {
        const int bid   = blockIdx.x - FB_CHAIN_BLOCKS;
        const int r     = bid & 31;
        const int chunk = bid >> 5;
        const int tid   = threadIdx.x;
        const float4* slab = (const float4*)(core + (size_t)r * VOC * RNK);
        const int base = chunk * 2048 + tid;
        float a0 = 0.f, a1 = 0.f, a2 = 0.f, a3 = 0.f;
        #pragma unroll
        for (int i = 0; i < 16; ++i) {
            float4 v = slab[base + i * 128];
            a0 += v.x; a1 += v.y; a2 += v.z; a3 += v.w;
        }
        float* ml = shmem;
        if (tid < RNK) ml[tid] = 0.f;
        __syncthreads();
        const int s0 = (tid & 7) * 4;
        atomicAdd(&ml[s0 + 0], a0);
        atomicAdd(&ml[s0 + 1], a1);
        atomicAdd(&ml[s0 + 2], a2);
        atomicAdd(&ml[s0 + 3], a3);
        __syncthreads();
        if (tid < RNK) atomicAdd(&gm[r * RNK + tid], ml[tid]);
    }
}

__global__ void fb_zchain_kernel(const float* __restrict__ gm,
                                 const float* __restrict__ alpha,
                                 const float* __restrict__ beta,
                                 float* __restrict__ out) {
    const int lane = threadIdx.x & 63;
    const int s    = lane & 31;
    const int half = lane >> 5;
    float col[16];
    #pragma unroll
    for (int i = 0; i < 16; ++i) col[i] = gm[(half * 16 + i) * RNK + s];
    float v = alpha[s];
    #pragma unroll
    for (int t = 0; t < SEQ; ++t) {
        float a0 = 0.f, a1 = 0.f, a2 = 0.f, a3 = 0.f;
        #pragma unroll
        for (int i = 0; i < 16; i += 4) {
            a0 = fmaf(__shfl(v, half * 16 + i + 0, 64), col[i + 0], a0);
            a1 = fmaf(__shfl(v, half * 16 + i + 1, 64), col[i + 1], a1);
            a2 = fmaf(__shfl(v, half * 16 + i + 2, 64), col[i + 2], a2);
            a3 = fmaf(__shfl(v, half * 16 + i + 3, 64), col[i + 3], a3);
        }
        const float acc = (a0 + a1) + (a2 + a3);
        v = acc + __shfl_xor(acc, 32, 64);
    }
    float z = v * beta[s];
    #pragma unroll
    for (int m = 16; m >= 1; m >>= 1) z += __shfl_xor(z, m, 64);
    if (lane == 0) out[BSZ] = z * (float)BSZ;
}

// ===========================================================================

extern "C" void kernel_launch(void* const* d_in, const int* in_sizes, int n_in,
                              void* d_out, int out_size, void* d_ws, size_t ws_size,
                              hipStream_t stream) {
    const int*   y     = (const int*)d_in[0];
    const float* alpha = (const float*)d_in[1];
    const float* beta  = (const float*)d_in[2];
    const float* core  = (const float*)d_in[3];
    float*          out    = (float*)d_out;
    float*          gm     = (float*)d_ws;                      // 1024 f32
    unsigned*       bitmap = (unsigned*)(gm + 1024);            // 1024 u32
    unsigned short* staged = (unsigned short*)(bitmap + 1024);  // VOC*1024 bf16

    if (ws_size >= WS_NEEDED) {
        hipMemsetAsync(d_ws, 0, 8192, stream);                  // gm + bitmap
        bitmap_kernel<<<48, 256, 0, stream>>>(y, bitmap);
        transpose_reduce_kernel<<<TP_BLOCKS, 256, 0, stream>>>(core, gm, bitmap, staged);
        chainz_staged_kernel<<<BSZ + 1, 64, 0, stream>>>(staged, y, alpha, beta, gm, out);
    } else {
        hipMemsetAsync(gm, 0, RNK * RNK * sizeof(float), stream);
        fb_fused_kernel<<<FB_CHAIN_BLOCKS + FB_REDUCE_BLOCKS, FB_BLOCK, 0, stream>>>(
            core, y, alpha, beta, out, gm);
        fb_zchain_kernel<<<1, 64, 0, stream>>>(gm, alpha, beta, out);
    }
}